// Round 1
// baseline (856.897 us; speedup 1.0000x reference)
//
#include <hip/hip_runtime.h>

#define NN 50000
#define FF 64
#define EE 800000

// xb[n] = W2 @ x[n], where W2 = W[:, 64:128], W row-major [64][128]
__global__ __launch_bounds__(256) void xb_kernel(
    const float* __restrict__ x, const float* __restrict__ W,
    float* __restrict__ xb)
{
    __shared__ float W2[64][65];  // +1 pad: lane f reads bank (f+k)%32 -> conflict-free
    for (int i = threadIdx.x; i < 64 * 64; i += 256) {
        int r = i >> 6, c = i & 63;
        W2[r][c] = W[r * 128 + 64 + c];
    }
    __syncthreads();
    const int wave = threadIdx.x >> 6;
    const int lane = threadIdx.x & 63;   // output feature f
    const int nwaves = gridDim.x * 4;
    for (int n = blockIdx.x * 4 + wave; n < NN; n += nwaves) {
        const float* xr = x + n * FF;
        float s = 0.f;
        #pragma unroll
        for (int k = 0; k < FF; ++k)
            s += W2[lane][k] * xr[k];     // xr[k]: uniform address -> broadcast
        xb[n * FF + lane] = s;
    }
}

// For each edge e: acc[dst] += xb[src]; cnt[dst] += 1
// 16 threads per edge, each handles a float4 slice.
__global__ __launch_bounds__(256) void scatter_kernel(
    const int* __restrict__ idx, const float* __restrict__ xb,
    float* __restrict__ acc, float* __restrict__ cnt)
{
    int gid = blockIdx.x * 256 + threadIdx.x;
    int e = gid >> 4;
    if (e >= EE) return;
    int q = gid & 15;
    int src = idx[e];         // edge_index[0][e]
    int dst = idx[EE + e];    // edge_index[1][e]
    const float4 v = *reinterpret_cast<const float4*>(xb + (size_t)src * FF + q * 4);
    float* o = acc + (size_t)dst * FF + q * 4;
    atomicAdd(o + 0, v.x);
    atomicAdd(o + 1, v.y);
    atomicAdd(o + 2, v.z);
    atomicAdd(o + 3, v.w);
    if (q == 0) atomicAdd(cnt + dst, 1.0f);
}

// out[n][f] = cnt>0 ? (W1-W2)[f]·x[n] + b[f] + acc[n][f]/cnt : 0
__global__ __launch_bounds__(256) void finalize_kernel(
    const float* __restrict__ x, const float* __restrict__ W,
    const float* __restrict__ b, const float* __restrict__ cnt,
    float* __restrict__ out)
{
    __shared__ float WA[64][65];
    __shared__ float bl[64];
    for (int i = threadIdx.x; i < 64 * 64; i += 256) {
        int r = i >> 6, c = i & 63;
        WA[r][c] = W[r * 128 + c] - W[r * 128 + 64 + c];
    }
    if (threadIdx.x < 64) bl[threadIdx.x] = b[threadIdx.x];
    __syncthreads();
    const int wave = threadIdx.x >> 6;
    const int lane = threadIdx.x & 63;
    const int nwaves = gridDim.x * 4;
    for (int n = blockIdx.x * 4 + wave; n < NN; n += nwaves) {
        const float* xr = x + n * FF;
        float a = 0.f;
        #pragma unroll
        for (int k = 0; k < FF; ++k)
            a += WA[lane][k] * xr[k];
        float c = cnt[n];
        float o = out[(size_t)n * FF + lane];
        out[(size_t)n * FF + lane] = (c > 0.f) ? (a + bl[lane] + o / c) : 0.f;
    }
}

extern "C" void kernel_launch(void* const* d_in, const int* in_sizes, int n_in,
                              void* d_out, int out_size, void* d_ws, size_t ws_size,
                              hipStream_t stream) {
    const float* x   = (const float*)d_in[0];
    const int*   idx = (const int*)d_in[1];   // [2][E] int32
    const float* W   = (const float*)d_in[2]; // [64][128]
    const float* b   = (const float*)d_in[3]; // [64]
    float* out = (float*)d_out;               // [NN][FF], also the scatter accumulator
    float* xb  = (float*)d_ws;                // [NN][FF]
    float* cnt = xb + (size_t)NN * FF;        // [NN]

    hipMemsetAsync(out, 0, (size_t)NN * FF * sizeof(float), stream);
    hipMemsetAsync(cnt, 0, (size_t)NN * sizeof(float), stream);

    xb_kernel<<<1024, 256, 0, stream>>>(x, W, xb);
    scatter_kernel<<<(EE * 16 + 255) / 256, 256, 0, stream>>>(idx, xb, out, cnt);
    finalize_kernel<<<1024, 256, 0, stream>>>(x, W, b, cnt, out);
}

// Round 2
// 298.585 us; speedup vs baseline: 2.8699x; 2.8699x over previous
//
#include <hip/hip_runtime.h>

#define NN 50000
#define FF 64
#define EE 800000
#define SCAN_BLK 1024
#define NSB 49   // ceil(NN / SCAN_BLK)

// cnt[dst]++ per edge
__global__ __launch_bounds__(256) void hist_kernel(const int* __restrict__ idx,
                                                   int* __restrict__ cnt) {
    int e = blockIdx.x * 256 + threadIdx.x;
    if (e < EE) atomicAdd(&cnt[idx[EE + e]], 1);
}

// bsum[b] = sum of cnt over block b's 1024 elements
__global__ __launch_bounds__(256) void part_sum_kernel(const int* __restrict__ cnt,
                                                       int* __restrict__ bsum) {
    __shared__ int red[256];
    int base = blockIdx.x * SCAN_BLK + threadIdx.x * 4;
    int s = 0;
    #pragma unroll
    for (int j = 0; j < 4; ++j) { int i = base + j; if (i < NN) s += cnt[i]; }
    red[threadIdx.x] = s;
    __syncthreads();
    for (int off = 128; off > 0; off >>= 1) {
        if (threadIdx.x < off) red[threadIdx.x] += red[threadIdx.x + off];
        __syncthreads();
    }
    if (threadIdx.x == 0) bsum[blockIdx.x] = red[0];
}

// serial exclusive scan of the 49 block sums (tiny)
__global__ void mid_scan_kernel(int* bsum) {
    if (threadIdx.x == 0) {
        int c = 0;
        for (int i = 0; i < NSB; ++i) { int t = bsum[i]; bsum[i] = c; c += t; }
    }
}

// offset[i] = exclusive scan of cnt (block-local scan + bsum carry)
__global__ __launch_bounds__(256) void offset_kernel(const int* __restrict__ cnt,
                                                     const int* __restrict__ bsum,
                                                     int* __restrict__ offset) {
    __shared__ int sc[256];
    int t = threadIdx.x;
    int base = blockIdx.x * SCAN_BLK + t * 4;
    int v[4]; int tsum = 0;
    #pragma unroll
    for (int j = 0; j < 4; ++j) { int i = base + j; v[j] = (i < NN) ? cnt[i] : 0; tsum += v[j]; }
    sc[t] = tsum;
    __syncthreads();
    for (int off = 1; off < 256; off <<= 1) {           // inclusive Hillis-Steele
        int add = (t >= off) ? sc[t - off] : 0;
        __syncthreads();
        sc[t] += add;
        __syncthreads();
    }
    int pre = bsum[blockIdx.x] + sc[t] - tsum;          // exclusive across threads
    #pragma unroll
    for (int j = 0; j < 4; ++j) { int i = base + j; if (i < NN) offset[i] = pre; pre += v[j]; }
}

// bucket-fill: ssrc[offset[dst]++] = src. After this, offset[n] == start of n+1.
__global__ __launch_bounds__(256) void fill_kernel(const int* __restrict__ idx,
                                                   int* __restrict__ offset,
                                                   int* __restrict__ ssrc) {
    int e = blockIdx.x * 256 + threadIdx.x;
    if (e >= EE) return;
    int src = idx[e], dst = idx[EE + e];
    int pos = atomicAdd(&offset[dst], 1);
    ssrc[pos] = src;
}

// wave per node: gather-sum x[src] rows, then out = (W1-W2)x[n] + b + W2*sum/cnt
__global__ __launch_bounds__(256) void aggregate_kernel(
    const float* __restrict__ x, const float* __restrict__ W,
    const float* __restrict__ b, const int* __restrict__ offset,
    const int* __restrict__ ssrc, float* __restrict__ out)
{
    __shared__ float WA[64][65];   // W1 - W2, +1 pad -> 2-way max (free)
    __shared__ float W2s[64][65];
    __shared__ float bl[64];
    for (int i = threadIdx.x; i < 4096; i += 256) {
        int r = i >> 6, c = i & 63;
        float w2 = W[r * 128 + 64 + c];
        WA[r][c]  = W[r * 128 + c] - w2;
        W2s[r][c] = w2;
    }
    if (threadIdx.x < 64) bl[threadIdx.x] = b[threadIdx.x];
    __syncthreads();

    const int wid = threadIdx.x >> 6, lane = threadIdx.x & 63;
    const int nw = gridDim.x * 4;
    for (int n = blockIdx.x * 4 + wid; n < NN; n += nw) {
        const int s  = (n == 0) ? 0 : offset[n - 1];   // post-fill: = orig offset[n]
        const int e_ = offset[n];                      // post-fill: = orig offset[n+1]
        const int c  = e_ - s;                         // = cnt[n]
        float sum = 0.f;
        int j = s;
        for (; j + 4 <= e_; j += 4) {                  // 4-way unroll for MLP
            int s0 = ssrc[j], s1 = ssrc[j+1], s2 = ssrc[j+2], s3 = ssrc[j+3];
            float a0 = x[(size_t)s0 * FF + lane];
            float a1 = x[(size_t)s1 * FF + lane];
            float a2 = x[(size_t)s2 * FF + lane];
            float a3 = x[(size_t)s3 * FF + lane];
            sum += (a0 + a1) + (a2 + a3);
        }
        for (; j < e_; ++j) sum += x[(size_t)ssrc[j] * FF + lane];

        float xv = x[(size_t)n * FF + lane];
        float a1 = bl[lane], a2 = 0.f;
        #pragma unroll
        for (int k = 0; k < 64; ++k) {                 // k const after unroll -> readlane
            float xk = __shfl(xv, k);
            float sk = __shfl(sum, k);
            a1 += WA[lane][k] * xk;
            a2 += W2s[lane][k] * sk;
        }
        out[(size_t)n * FF + lane] = (c > 0) ? (a1 + a2 / (float)c) : 0.f;
    }
}

extern "C" void kernel_launch(void* const* d_in, const int* in_sizes, int n_in,
                              void* d_out, int out_size, void* d_ws, size_t ws_size,
                              hipStream_t stream) {
    const float* x   = (const float*)d_in[0];
    const int*   idx = (const int*)d_in[1];   // [2][E] int32
    const float* W   = (const float*)d_in[2]; // [64][128]
    const float* b   = (const float*)d_in[3]; // [64]
    float* out = (float*)d_out;

    int* cnt    = (int*)d_ws;            // [NN]
    int* offset = cnt + NN;              // [NN]
    int* bsum   = offset + NN;           // [64]
    int* ssrc   = bsum + 64;             // [EE]

    hipMemsetAsync(cnt, 0, NN * sizeof(int), stream);

    hist_kernel   <<<(EE + 255) / 256, 256, 0, stream>>>(idx, cnt);
    part_sum_kernel<<<NSB, 256, 0, stream>>>(cnt, bsum);
    mid_scan_kernel<<<1, 64, 0, stream>>>(bsum);
    offset_kernel <<<NSB, 256, 0, stream>>>(cnt, bsum, offset);
    fill_kernel   <<<(EE + 255) / 256, 256, 0, stream>>>(idx, offset, ssrc);
    aggregate_kernel<<<1024, 256, 0, stream>>>(x, W, b, offset, ssrc, out);
}